// Round 3
// baseline (2570.775 us; speedup 1.0000x reference)
//
#include <hip/hip_runtime.h>
#include <hip/hip_bf16.h>
#include <hip/hip_fp16.h>
#include <stdint.h>

#define FEATS   512
#define HIDDEN  64
#define CLASSES 16
#define EMB_DIM 7
#define ADJ_H   11
#define DEPTH   10
#define NSLICE  4
#define SLICE_F 16   // features per slice (16 fp16 = 32 B rows)

typedef __hip_bfloat16 bf16;
typedef __attribute__((ext_vector_type(8))) short short8;
typedef __attribute__((ext_vector_type(4))) float f32x4;

__device__ __forceinline__ float b2f(bf16 v) { return __bfloat162float(v); }

// ---------------- dtype detect: 1 = bf16, 0 = f32 ----------------
__global__ void k_detect(const unsigned short* __restrict__ xs, int* __restrict__ flag) {
    __shared__ int cnt;
    if (threadIdx.x == 0) cnt = 0;
    __syncthreads();
    int c = 0;
    for (int i = threadIdx.x; i < 4096; i += 256) {
        unsigned e = (xs[i] >> 7) & 0xFFu;
        if (e >= 134u) c++;
    }
    atomicAdd(&cnt, c);
    __syncthreads();
    if (threadIdx.x == 0) *flag = (cnt < 64) ? 1 : 0;
}

// ---------------- degree ----------------
__global__ __launch_bounds__(256) void k_deg(const int* __restrict__ edges,
                                             int* __restrict__ deg, int E) {
    int e = blockIdx.x * 256 + threadIdx.x;
    if (e < E) atomicAdd(&deg[edges[E + e]], 1);
}

// ---------------- exclusive scan (+ degree histogram for balanced sort) ----------------
__global__ __launch_bounds__(256) void k_scan1(const int* __restrict__ deg,
                                               int* __restrict__ offs,
                                               int* __restrict__ bsum,
                                               int* __restrict__ hist, int n) {
    __shared__ int ts[256];
    __shared__ int hb[256];
    int t = threadIdx.x;
    hb[t] = 0;
    int base = blockIdx.x * 1024 + t * 4;
    int v0 = (base + 0 < n) ? deg[base + 0] : 0;
    int v1 = (base + 1 < n) ? deg[base + 1] : 0;
    int v2 = (base + 2 < n) ? deg[base + 2] : 0;
    int v3 = (base + 3 < n) ? deg[base + 3] : 0;
    int tsum = v0 + v1 + v2 + v3;
    ts[t] = tsum;
    __syncthreads();
    if (base + 0 < n) atomicAdd(&hb[min(v0, 255)], 1);
    if (base + 1 < n) atomicAdd(&hb[min(v1, 255)], 1);
    if (base + 2 < n) atomicAdd(&hb[min(v2, 255)], 1);
    if (base + 3 < n) atomicAdd(&hb[min(v3, 255)], 1);
    for (int d = 1; d < 256; d <<= 1) {
        int add = (t >= d) ? ts[t - d] : 0;
        __syncthreads();
        ts[t] += add;
        __syncthreads();
    }
    int excl = ts[t] - tsum;
    if (base + 0 < n) offs[base + 0] = excl;
    if (base + 1 < n) offs[base + 1] = excl + v0;
    if (base + 2 < n) offs[base + 2] = excl + v0 + v1;
    if (base + 3 < n) offs[base + 3] = excl + v0 + v1 + v2;
    if (t == 255) bsum[blockIdx.x] = ts[255];
    if (hb[t]) atomicAdd(&hist[t], hb[t]);
}

__global__ void k_scan2(const int* __restrict__ bsum, int* __restrict__ bpref,
                        int* __restrict__ offs, int nb, int n) {
    if (threadIdx.x == 0 && blockIdx.x == 0) {
        int run = 0;
        int lim = (nb < 4096) ? nb : 4096;
        for (int i = 0; i < lim; ++i) { bpref[i] = run; run += bsum[i]; }
        offs[n] = run;
    }
}

__global__ __launch_bounds__(256) void k_scan3(int* __restrict__ offs,
                                               const int* __restrict__ bpref, int n) {
    int i = blockIdx.x * 256 + threadIdx.x;
    if (i < n) offs[i] += bpref[i >> 10];
}

// ---------------- degree-bin exclusive scan -> hcur ----------------
__global__ void k_hscan(const int* __restrict__ hist, int* __restrict__ hcur) {
    __shared__ int s[256];
    int t = threadIdx.x;
    int orig = hist[t];
    s[t] = orig;
    __syncthreads();
    for (int d = 1; d < 256; d <<= 1) {
        int add = (t >= d) ? s[t - d] : 0;
        __syncthreads();
        s[t] += add;
        __syncthreads();
    }
    hcur[t] = s[t] - orig;
}

// ---------------- scatter nodes into degree-sorted permutation ----------------
// Block-local LDS histogram: one global atomic per (block, bin) instead of per
// node -> kills the same-address atomic serialization (was 262 us in round 1).
__global__ __launch_bounds__(256) void k_scatter(const int* __restrict__ deg,
                                                 int* __restrict__ hcur,
                                                 int* __restrict__ perm, int n) {
    __shared__ int lh[256];
    __shared__ int lbase[256];
    int t = threadIdx.x;
    lh[t] = 0;
    __syncthreads();
    int i = blockIdx.x * 256 + t;
    int d = 0, lpos = 0;
    bool v = i < n;
    if (v) {
        d = min(deg[i], 255);
        lpos = atomicAdd(&lh[d], 1);
    }
    __syncthreads();
    int c = lh[t];
    if (c) lbase[t] = atomicAdd(&hcur[t], c);
    __syncthreads();
    if (v) perm[lbase[d] + lpos] = i;
}

// ---------------- CSR fill: pack (src:17b | w:15b fixed-point x16384) ----------------
__global__ __launch_bounds__(256) void k_fill(const int* __restrict__ edges,
                                              const int* __restrict__ offs,
                                              int* __restrict__ cursor,
                                              const int* __restrict__ deg,
                                              unsigned* __restrict__ ew, int E) {
    int e = blockIdx.x * 256 + threadIdx.x;
    if (e < E) {
        int src = edges[e];
        int dst = edges[E + e];
        int pos = offs[dst] + atomicAdd(&cursor[dst], 1);
        int ds = deg[src], dd = deg[dst];
        float w = (ds > 0 ? rsqrtf((float)ds) : 0.f) * (dd > 0 ? rsqrtf((float)dd) : 0.f);
        int w15 = (int)(w * 16384.0f + 0.5f);
        if (w15 > 32767) w15 = 32767;
        ew[pos] = ((unsigned)src << 15) | (unsigned)w15;
    }
}

// ---------------- MLP constants (reads raw dtype via flag) ----------------
__global__ void k_mlpconst(const void* __restrict__ emb, const void* __restrict__ W_a1,
                           const void* __restrict__ b_a1, const void* __restrict__ W_a2,
                           const void* __restrict__ b_a2, const int* __restrict__ flag,
                           float* __restrict__ C) {
    int isbf = *flag;
    auto g = [&](const void* p, int i) -> float {
        return isbf ? b2f(((const bf16*)p)[i]) : ((const float*)p)[i];
    };
    int j = threadIdx.x;
    if (j < ADJ_H) {
        float c = g(b_a1, j);
        for (int k = 0; k < EMB_DIM; ++k)
            c += g(emb, k) * g(W_a1, (2 + k) * ADJ_H + j);
        C[j]      = c;
        C[11 + j] = g(W_a1, 0 * ADJ_H + j);
        C[22 + j] = g(W_a1, 1 * ADJ_H + j);
        C[33 + j] = g(W_a2, j);
    }
    if (j == 0) C[44] = g(b_a2, 0);
}

// ---------------- MFMA GEMM: h = x @ W + b -> fp16 SLAB layout [slice][node][16] ----------------
__global__ __launch_bounds__(256) void k_gemm_mfma(const void* __restrict__ xraw,
                                                   const int* __restrict__ flag,
                                                   const void* __restrict__ Wraw,
                                                   const void* __restrict__ braw,
                                                   __half* __restrict__ out, int n) {
    __shared__ short Wt[64 * 520];
    int t = threadIdx.x;
    int isbf = *flag;
    if (isbf) {
        const unsigned short* wr = (const unsigned short*)Wraw;
        for (int e = t; e < FEATS * HIDDEN; e += 256)
            Wt[(e & 63) * 520 + (e >> 6)] = (short)wr[e];
    } else {
        const float* wr = (const float*)Wraw;
        for (int e = t; e < FEATS * HIDDEN; e += 256)
            Wt[(e & 63) * 520 + (e >> 6)] = (short)(__float_as_uint(wr[e]) >> 16);
    }
    __syncthreads();

    int wv = t >> 6;
    int lane = t & 63;
    int quad = lane >> 4, l16 = lane & 15;
    int rowbase = blockIdx.x * 256 + wv * 64;

    f32x4 acc[4][4];
    #pragma unroll
    for (int a = 0; a < 4; ++a)
        #pragma unroll
        for (int b = 0; b < 4; ++b)
            acc[a][b] = (f32x4){0.f, 0.f, 0.f, 0.f};

    if (isbf) {
        const short* x = (const short*)xraw;
        for (int ks = 0; ks < 16; ++ks) {
            short8 bfr[4];
            #pragma unroll
            for (int nt = 0; nt < 4; ++nt)
                bfr[nt] = *(const short8*)&Wt[(nt * 16 + l16) * 520 + ks * 32 + quad * 8];
            #pragma unroll
            for (int rt = 0; rt < 4; ++rt) {
                int arow = rowbase + rt * 16 + l16;
                if (arow >= n) arow = n - 1;
                short8 a = *(const short8*)(x + (size_t)arow * FEATS + ks * 32 + quad * 8);
                #pragma unroll
                for (int nt = 0; nt < 4; ++nt)
                    acc[rt][nt] = __builtin_amdgcn_mfma_f32_16x16x32_bf16(a, bfr[nt], acc[rt][nt], 0, 0, 0);
            }
        }
    } else {
        const float* x = (const float*)xraw;
        for (int ks = 0; ks < 16; ++ks) {
            short8 bfr[4];
            #pragma unroll
            for (int nt = 0; nt < 4; ++nt)
                bfr[nt] = *(const short8*)&Wt[(nt * 16 + l16) * 520 + ks * 32 + quad * 8];
            #pragma unroll
            for (int rt = 0; rt < 4; ++rt) {
                int arow = rowbase + rt * 16 + l16;
                if (arow >= n) arow = n - 1;
                const float* ap = x + (size_t)arow * FEATS + ks * 32 + quad * 8;
                short8 a;
                #pragma unroll
                for (int j = 0; j < 8; ++j)
                    a[j] = (short)(__float_as_uint(ap[j]) >> 16);
                #pragma unroll
                for (int nt = 0; nt < 4; ++nt)
                    acc[rt][nt] = __builtin_amdgcn_mfma_f32_16x16x32_bf16(a, bfr[nt], acc[rt][nt], 0, 0, 0);
            }
        }
    }

    float bias[4];
    #pragma unroll
    for (int nt = 0; nt < 4; ++nt)
        bias[nt] = isbf ? b2f(((const bf16*)braw)[nt * 16 + l16])
                        : ((const float*)braw)[nt * 16 + l16];

    size_t slab = (size_t)n * SLICE_F;
    #pragma unroll
    for (int rt = 0; rt < 4; ++rt)
        #pragma unroll
        for (int nt = 0; nt < 4; ++nt) {
            #pragma unroll
            for (int r = 0; r < 4; ++r) {
                int grow = rowbase + rt * 16 + quad * 4 + r;
                if (grow < n)
                    out[(size_t)nt * slab + (size_t)grow * SLICE_F + l16] =
                        __float2half(acc[rt][nt][r] + bias[nt]);
            }
        }
}

// ---------------- conv on ONE 16-feature slab (3.2 MB -> fits per-XCD L2) ----------------
// 16 nodes/wave, 4 lanes/node, 8 B (4 fp16) per lane = 32 B gather per edge.
// Degree-sorted perm keeps the 16 trip counts uniform. ew/h0/hout use
// non-temporal accesses so streams don't evict the L2-resident slab.
__device__ __forceinline__ void acc4e(float* acc, unsigned long long r, float w) {
    unsigned lo = (unsigned)r, hi = (unsigned)(r >> 32);
    float2 f0 = __half22float2(*(const __half2*)&lo);
    float2 f1 = __half22float2(*(const __half2*)&hi);
    acc[0] += w * f0.x; acc[1] += w * f0.y;
    acc[2] += w * f1.x; acc[3] += w * f1.y;
}

__global__ __launch_bounds__(256) void k_conv(const int* __restrict__ offs,
                                              const int* __restrict__ perm,
                                              const unsigned* __restrict__ ew,
                                              const __half* __restrict__ hin,
                                              const __half* __restrict__ h0,
                                              __half* __restrict__ hout, int n) {
    int wv = (blockIdx.x * 256 + threadIdx.x) >> 6;
    int lane = threadIdx.x & 63;
    int sub = lane >> 2;          // 0..15 : node within wave
    int li  = lane & 3;           // 4 lanes x 8 B = 32 B row slice
    int idx = wv * 16 + sub;
    bool valid = idx < n;
    int node  = valid ? perm[idx] : 0;
    int start = valid ? offs[node] : 0;
    int end   = valid ? offs[node + 1] : 0;

    float acc[4] = {0.f, 0.f, 0.f, 0.f};

    int p = start;
    for (; p + 8 <= end; p += 8) {
        unsigned u0 = __builtin_nontemporal_load(&ew[p + 0]);
        unsigned u1 = __builtin_nontemporal_load(&ew[p + 1]);
        unsigned u2 = __builtin_nontemporal_load(&ew[p + 2]);
        unsigned u3 = __builtin_nontemporal_load(&ew[p + 3]);
        unsigned u4 = __builtin_nontemporal_load(&ew[p + 4]);
        unsigned u5 = __builtin_nontemporal_load(&ew[p + 5]);
        unsigned u6 = __builtin_nontemporal_load(&ew[p + 6]);
        unsigned u7 = __builtin_nontemporal_load(&ew[p + 7]);
        unsigned long long r0 = *(const unsigned long long*)(hin + (size_t)(u0 >> 15) * SLICE_F + li * 4);
        unsigned long long r1 = *(const unsigned long long*)(hin + (size_t)(u1 >> 15) * SLICE_F + li * 4);
        unsigned long long r2 = *(const unsigned long long*)(hin + (size_t)(u2 >> 15) * SLICE_F + li * 4);
        unsigned long long r3 = *(const unsigned long long*)(hin + (size_t)(u3 >> 15) * SLICE_F + li * 4);
        unsigned long long r4 = *(const unsigned long long*)(hin + (size_t)(u4 >> 15) * SLICE_F + li * 4);
        unsigned long long r5 = *(const unsigned long long*)(hin + (size_t)(u5 >> 15) * SLICE_F + li * 4);
        unsigned long long r6 = *(const unsigned long long*)(hin + (size_t)(u6 >> 15) * SLICE_F + li * 4);
        unsigned long long r7 = *(const unsigned long long*)(hin + (size_t)(u7 >> 15) * SLICE_F + li * 4);
        acc4e(acc, r0, (float)(u0 & 0x7FFFu));
        acc4e(acc, r1, (float)(u1 & 0x7FFFu));
        acc4e(acc, r2, (float)(u2 & 0x7FFFu));
        acc4e(acc, r3, (float)(u3 & 0x7FFFu));
        acc4e(acc, r4, (float)(u4 & 0x7FFFu));
        acc4e(acc, r5, (float)(u5 & 0x7FFFu));
        acc4e(acc, r6, (float)(u6 & 0x7FFFu));
        acc4e(acc, r7, (float)(u7 & 0x7FFFu));
    }
    if (p + 4 <= end) {
        unsigned u0 = __builtin_nontemporal_load(&ew[p + 0]);
        unsigned u1 = __builtin_nontemporal_load(&ew[p + 1]);
        unsigned u2 = __builtin_nontemporal_load(&ew[p + 2]);
        unsigned u3 = __builtin_nontemporal_load(&ew[p + 3]);
        unsigned long long r0 = *(const unsigned long long*)(hin + (size_t)(u0 >> 15) * SLICE_F + li * 4);
        unsigned long long r1 = *(const unsigned long long*)(hin + (size_t)(u1 >> 15) * SLICE_F + li * 4);
        unsigned long long r2 = *(const unsigned long long*)(hin + (size_t)(u2 >> 15) * SLICE_F + li * 4);
        unsigned long long r3 = *(const unsigned long long*)(hin + (size_t)(u3 >> 15) * SLICE_F + li * 4);
        acc4e(acc, r0, (float)(u0 & 0x7FFFu));
        acc4e(acc, r1, (float)(u1 & 0x7FFFu));
        acc4e(acc, r2, (float)(u2 & 0x7FFFu));
        acc4e(acc, r3, (float)(u3 & 0x7FFFu));
        p += 4;
    }
    for (; p < end; ++p) {
        unsigned u = __builtin_nontemporal_load(&ew[p]);
        unsigned long long r = *(const unsigned long long*)(hin + (size_t)(u >> 15) * SLICE_F + li * 4);
        acc4e(acc, r, (float)(u & 0x7FFFu));
    }

    if (valid) {
        size_t o = (size_t)node * SLICE_F + li * 4;
        unsigned long long hv = __builtin_nontemporal_load((const unsigned long long*)(h0 + o));
        unsigned lo = (unsigned)hv, hi = (unsigned)(hv >> 32);
        float2 g0 = __half22float2(*(const __half2*)&lo);
        float2 g1 = __half22float2(*(const __half2*)&hi);
        __half2 o0 = __floats2half2_rn(
            0.9f * (1.0f / 16384.0f) * acc[0] + 0.1f * g0.x,
            0.9f * (1.0f / 16384.0f) * acc[1] + 0.1f * g0.y);
        __half2 o1 = __floats2half2_rn(
            0.9f * (1.0f / 16384.0f) * acc[2] + 0.1f * g1.x,
            0.9f * (1.0f / 16384.0f) * acc[3] + 0.1f * g1.y);
        unsigned w0 = *(unsigned*)&o0, w1 = *(unsigned*)&o1;
        unsigned long long ov = (unsigned long long)w0 | ((unsigned long long)w1 << 32);
        __builtin_nontemporal_store(ov, (unsigned long long*)(hout + o));
    }
}

// ---------------- elementwise edge-MLP (in-place on h0; layout-agnostic) ----------------
__global__ __launch_bounds__(256) void k_mlp(__half* __restrict__ h0io,
                                             const __half* __restrict__ hc,
                                             const float* __restrict__ C, int total2) {
    int i = blockIdx.x * 256 + threadIdx.x;
    if (i >= total2) return;
    float2 hv  = __half22float2(((const __half2*)hc)[i]);
    float2 h0v = __half22float2(((const __half2*)h0io)[i]);
    float sx = C[44], sy = C[44];
    #pragma unroll
    for (int j = 0; j < ADJ_H; ++j) {
        float bj = C[j], wh = C[11 + j], w0 = C[22 + j], wo = C[33 + j];
        float zx = bj + hv.x * wh + h0v.x * w0;
        float zy = bj + hv.y * wh + h0v.y * w0;
        zx = (zx > 0.f) ? zx : 0.01f * zx;
        zy = (zy > 0.f) ? zy : 0.01f * zy;
        sx += zx * wo;
        sy += zy * wo;
    }
    ((__half2*)h0io)[i] = __floats2half2_rn(0.5f * sx, 0.5f * sy);
}

// ---------------- classifier (reads slab layout) ----------------
__global__ __launch_bounds__(256) void k_cls(const __half* __restrict__ h,
                                             const void* __restrict__ Wcraw,
                                             const void* __restrict__ bcraw,
                                             void* __restrict__ outraw,
                                             const int* __restrict__ flag, int n) {
    __shared__ float hs[64][65];
    __shared__ float ws[64 * 16];
    __shared__ float bs[16];
    int t = threadIdx.x;
    int base = blockIdx.x * 64;
    int isbf = *flag;
    size_t slab = (size_t)n * SLICE_F;
    for (int it = 0; it < 16; ++it) {
        int e = it * 256 + t;
        int rr = e >> 6, cc = e & 63;
        int g = base + rr;
        hs[rr][cc] = (g < n)
            ? __half2float(h[(size_t)(cc >> 4) * slab + (size_t)g * SLICE_F + (cc & 15)])
            : 0.f;
    }
    for (int it = 0; it < 4; ++it) {
        int e = it * 256 + t;
        ws[e] = isbf ? b2f(((const bf16*)Wcraw)[e]) : ((const float*)Wcraw)[e];
    }
    if (t < 16) bs[t] = isbf ? b2f(((const bf16*)bcraw)[t]) : ((const float*)bcraw)[t];
    __syncthreads();
    for (int q = 0; q < 4; ++q) {
        int e = q * 256 + t;
        int node = e >> 4, cls = e & 15;
        float acc = bs[cls];
        #pragma unroll 8
        for (int k = 0; k < HIDDEN; ++k)
            acc += hs[node][k] * ws[k * 16 + cls];
        int g = base + node;
        if (g < n) {
            size_t oi = (size_t)g * CLASSES + cls;
            if (isbf) ((bf16*)outraw)[oi] = __float2bfloat16(acc);
            else      ((float*)outraw)[oi] = acc;
        }
    }
}

extern "C" void kernel_launch(void* const* d_in, const int* in_sizes, int n_in,
                              void* d_out, int out_size, void* d_ws, size_t ws_size,
                              hipStream_t stream) {
    const void* x     = d_in[0];
    const int*  edges = (const int*)d_in[1];
    const void* W_dim = d_in[2];
    const void* b_dim = d_in[3];
    const void* emb   = d_in[4];
    const void* W_a1  = d_in[5];
    const void* b_a1  = d_in[6];
    const void* W_a2  = d_in[7];
    const void* b_a2  = d_in[8];
    const void* Wcls  = d_in[9];
    const void* bcls  = d_in[10];

    const int n = in_sizes[0] / FEATS;     // 100000
    const int E = in_sizes[1] / 2;         // 1600000

    char* w = (char*)d_ws;
    size_t off = 0;
    auto alloc = [&](size_t bytes) -> void* {
        void* p = w + off;
        off = (off + bytes + 255) & ~(size_t)255;
        return p;
    };
    // zero-initialized region first: deg, cursor, hist
    int*      deg    = (int*)     alloc((size_t)n * 4);
    int*      cursor = (int*)     alloc((size_t)n * 4);
    int*      hist   = (int*)     alloc(256 * 4);
    size_t zero_bytes = off;
    int*      hcur   = (int*)     alloc(256 * 4);
    int*      perm   = (int*)     alloc((size_t)n * 4);
    int*      offs   = (int*)     alloc((size_t)(n + 1) * 4);
    int*      bsum   = (int*)     alloc(4096 * 4);
    int*      bpref  = (int*)     alloc(4096 * 4);
    unsigned* ew     = (unsigned*)alloc((size_t)E * 4);
    float*    consts = (float*)   alloc(64 * 4);
    int*      flag   = (int*)     alloc(256);
    __half*   buf0   = (__half*)  alloc((size_t)n * HIDDEN * 2);
    __half*   bufA   = (__half*)  alloc((size_t)n * HIDDEN * 2);
    __half*   bufB   = (__half*)  alloc((size_t)n * HIDDEN * 2);

    int gE = (E + 255) / 256;
    int gN = (n + 255) / 256;
    int nb = (n + 1023) / 1024;
    int gConv = (n + 63) / 64;   // 4 waves/block, 16 nodes/wave

    hipMemsetAsync(d_ws, 0, zero_bytes, stream);

    k_detect<<<1, 256, 0, stream>>>((const unsigned short*)x, flag);

    k_deg  <<<gE, 256, 0, stream>>>(edges, deg, E);
    k_scan1<<<nb, 256, 0, stream>>>(deg, offs, bsum, hist, n);
    k_scan2<<<1, 64, 0, stream>>>(bsum, bpref, offs, nb, n);
    k_scan3<<<gN, 256, 0, stream>>>(offs, bpref, n);
    k_fill <<<gE, 256, 0, stream>>>(edges, offs, cursor, deg, ew, E);

    // degree-balanced node permutation (block-privatized scatter)
    k_hscan  <<<1, 256, 0, stream>>>(hist, hcur);
    k_scatter<<<gN, 256, 0, stream>>>(deg, hcur, perm, n);

    k_mlpconst<<<1, 64, 0, stream>>>(emb, W_a1, b_a1, W_a2, b_a2, flag, consts);

    k_gemm_mfma<<<(n + 255) / 256, 256, 0, stream>>>(x, flag, W_dim, b_dim, buf0, n);

    size_t slab = (size_t)n * SLICE_F;   // halves per slab

    // phase 1: slice-outer so one 3.2 MB slab stays L2-hot across 10 convs
    for (int s = 0; s < NSLICE; ++s) {
        const __half* hin = buf0 + (size_t)s * slab;
        for (int i = 0; i < DEPTH; ++i) {
            __half* ho = ((i & 1) ? bufB : bufA) + (size_t)s * slab;
            k_conv<<<gConv, 256, 0, stream>>>(offs, perm, ew, hin,
                                              buf0 + (size_t)s * slab, ho, n);
            hin = ho;
        }
    }
    k_mlp<<<(n * (HIDDEN / 2) + 255) / 256, 256, 0, stream>>>(buf0, bufB, consts, n * (HIDDEN / 2));

    // phase 2
    for (int s = 0; s < NSLICE; ++s) {
        const __half* hin = buf0 + (size_t)s * slab;
        for (int i = 0; i < DEPTH; ++i) {
            __half* ho = ((i & 1) ? bufB : bufA) + (size_t)s * slab;
            k_conv<<<gConv, 256, 0, stream>>>(offs, perm, ew, hin,
                                              buf0 + (size_t)s * slab, ho, n);
            hin = ho;
        }
    }
    k_cls<<<(n + 63) / 64, 256, 0, stream>>>(bufB, Wcls, bcls, d_out, flag, n);
}

// Round 5
// 1986.500 us; speedup vs baseline: 1.2941x; 1.2941x over previous
//
#include <hip/hip_runtime.h>
#include <hip/hip_bf16.h>
#include <hip/hip_fp16.h>
#include <stdint.h>

#define FEATS   512
#define HIDDEN  64
#define CLASSES 16
#define EMB_DIM 7
#define ADJ_H   11
#define DEPTH   10
#define NGRP    4     // source-row groups per conv (3.2 MB each -> fits 4 MB per-XCD L2)

typedef __hip_bfloat16 bf16;
typedef __attribute__((ext_vector_type(8))) short short8;
typedef __attribute__((ext_vector_type(4))) float f32x4;

__device__ __forceinline__ float b2f(bf16 v) { return __bfloat162float(v); }

// ---------------- dtype detect: 1 = bf16, 0 = f32 ----------------
__global__ void k_detect(const unsigned short* __restrict__ xs, int* __restrict__ flag) {
    __shared__ int cnt;
    if (threadIdx.x == 0) cnt = 0;
    __syncthreads();
    int c = 0;
    for (int i = threadIdx.x; i < 4096; i += 256) {
        unsigned e = (xs[i] >> 7) & 0xFFu;
        if (e >= 134u) c++;
    }
    atomicAdd(&cnt, c);
    __syncthreads();
    if (threadIdx.x == 0) *flag = (cnt < 64) ? 1 : 0;
}

// ---------------- total degree ----------------
__global__ __launch_bounds__(256) void k_deg(const int* __restrict__ edges,
                                             int* __restrict__ deg, int E) {
    int e = blockIdx.x * 256 + threadIdx.x;
    if (e < E) atomicAdd(&deg[edges[E + e]], 1);
}

// ---------------- degree histogram (LDS-privatized) ----------------
__global__ __launch_bounds__(256) void k_hist(const int* __restrict__ deg,
                                              int* __restrict__ hist, int n) {
    __shared__ int hb[256];
    int t = threadIdx.x;
    hb[t] = 0;
    __syncthreads();
    int i = blockIdx.x * 256 + t;
    if (i < n) atomicAdd(&hb[min(deg[i], 255)], 1);
    __syncthreads();
    if (hb[t]) atomicAdd(&hist[t], hb[t]);
}

// ---------------- degree-bin exclusive scan -> hcur ----------------
__global__ void k_hscan(const int* __restrict__ hist, int* __restrict__ hcur) {
    __shared__ int s[256];
    int t = threadIdx.x;
    int orig = hist[t];
    s[t] = orig;
    __syncthreads();
    for (int d = 1; d < 256; d <<= 1) {
        int add = (t >= d) ? s[t - d] : 0;
        __syncthreads();
        s[t] += add;
        __syncthreads();
    }
    hcur[t] = s[t] - orig;
}

// ---------------- scatter: perm (degree-sorted) + inverse ----------------
__global__ __launch_bounds__(256) void k_scatter(const int* __restrict__ deg,
                                                 int* __restrict__ hcur,
                                                 int* __restrict__ perm,
                                                 int* __restrict__ inv, int n) {
    __shared__ int lh[256];
    __shared__ int lbase[256];
    int t = threadIdx.x;
    lh[t] = 0;
    __syncthreads();
    int i = blockIdx.x * 256 + t;
    int d = 0, lpos = 0;
    bool v = i < n;
    if (v) {
        d = min(deg[i], 255);
        lpos = atomicAdd(&lh[d], 1);
    }
    __syncthreads();
    int c = lh[t];
    if (c) lbase[t] = atomicAdd(&hcur[t], c);
    __syncthreads();
    if (v) {
        int pos = lbase[d] + lpos;
        perm[pos] = i;
        inv[i] = pos;
    }
}

// ---------------- per-(group, dst) degree counts: deg4[g*n + dst] ----------------
__global__ __launch_bounds__(256) void k_deg4(const int* __restrict__ edges,
                                              const int* __restrict__ inv,
                                              int* __restrict__ deg4,
                                              int n, int E, int gsz) {
    int e = blockIdx.x * 256 + threadIdx.x;
    if (e < E) {
        int src = edges[e];
        int dst = edges[E + e];
        int g = min(NGRP - 1, inv[src] / gsz);
        atomicAdd(&deg4[(size_t)g * n + dst], 1);
    }
}

// ---------------- generic exclusive scan over m ints ----------------
__global__ __launch_bounds__(256) void k_scan1(const int* __restrict__ in,
                                               int* __restrict__ out,
                                               int* __restrict__ bsum, int m) {
    __shared__ int ts[256];
    int t = threadIdx.x;
    int base = blockIdx.x * 1024 + t * 4;
    int v0 = (base + 0 < m) ? in[base + 0] : 0;
    int v1 = (base + 1 < m) ? in[base + 1] : 0;
    int v2 = (base + 2 < m) ? in[base + 2] : 0;
    int v3 = (base + 3 < m) ? in[base + 3] : 0;
    int tsum = v0 + v1 + v2 + v3;
    ts[t] = tsum;
    __syncthreads();
    for (int d = 1; d < 256; d <<= 1) {
        int add = (t >= d) ? ts[t - d] : 0;
        __syncthreads();
        ts[t] += add;
        __syncthreads();
    }
    int excl = ts[t] - tsum;
    if (base + 0 < m) out[base + 0] = excl;
    if (base + 1 < m) out[base + 1] = excl + v0;
    if (base + 2 < m) out[base + 2] = excl + v0 + v1;
    if (base + 3 < m) out[base + 3] = excl + v0 + v1 + v2;
    if (t == 255) bsum[blockIdx.x] = ts[255];
}

__global__ void k_scan2(const int* __restrict__ bsum, int* __restrict__ bpref,
                        int* __restrict__ out, int nb, int m) {
    if (threadIdx.x == 0 && blockIdx.x == 0) {
        int run = 0;
        int lim = (nb < 4096) ? nb : 4096;
        for (int i = 0; i < lim; ++i) { bpref[i] = run; run += bsum[i]; }
        out[m] = run;
    }
}

__global__ __launch_bounds__(256) void k_scan3(int* __restrict__ out,
                                               const int* __restrict__ bpref, int m) {
    int i = blockIdx.x * 256 + threadIdx.x;
    if (i < m) out[i] += bpref[i >> 10];
}

// ---------------- CSR fill: group-major buckets, pack (pidx:17b | w:15b) ----------------
__global__ __launch_bounds__(256) void k_fill(const int* __restrict__ edges,
                                              const int* __restrict__ inv,
                                              const int* __restrict__ offs4,
                                              int* __restrict__ cursor4,
                                              const int* __restrict__ deg,
                                              unsigned* __restrict__ ew,
                                              int n, int E, int gsz) {
    int e = blockIdx.x * 256 + threadIdx.x;
    if (e < E) {
        int src = edges[e];
        int dst = edges[E + e];
        int pidx = inv[src];
        int g = min(NGRP - 1, pidx / gsz);
        size_t slot = (size_t)g * n + dst;
        int pos = offs4[slot] + atomicAdd(&cursor4[slot], 1);
        int ds = deg[src], dd = deg[dst];
        float w = (ds > 0 ? rsqrtf((float)ds) : 0.f) * (dd > 0 ? rsqrtf((float)dd) : 0.f);
        int w15 = (int)(w * 16384.0f + 0.5f);
        if (w15 > 32767) w15 = 32767;
        ew[pos] = ((unsigned)pidx << 15) | (unsigned)w15;
    }
}

// ---------------- meta: per-phase starts/lens in perm order (coalesced reads in conv) ----------------
__global__ __launch_bounds__(256) void k_meta(const int* __restrict__ perm,
                                              const int* __restrict__ offs4,
                                              int* __restrict__ startsS,
                                              unsigned short* __restrict__ lensS, int n) {
    int idx = blockIdx.x * 256 + threadIdx.x;
    if (idx < n) {
        int v = perm[idx];
        #pragma unroll
        for (int s = 0; s < NGRP; ++s) {
            int a = offs4[(size_t)s * n + v];
            int b = offs4[(size_t)s * n + v + 1];
            startsS[(size_t)s * n + idx] = a;
            lensS[(size_t)s * n + idx] = (unsigned short)(b - a);
        }
    }
}

// ---------------- MLP constants ----------------
__global__ void k_mlpconst(const void* __restrict__ emb, const void* __restrict__ W_a1,
                           const void* __restrict__ b_a1, const void* __restrict__ W_a2,
                           const void* __restrict__ b_a2, const int* __restrict__ flag,
                           float* __restrict__ C) {
    int isbf = *flag;
    auto g = [&](const void* p, int i) -> float {
        return isbf ? b2f(((const bf16*)p)[i]) : ((const float*)p)[i];
    };
    int j = threadIdx.x;
    if (j < ADJ_H) {
        float c = g(b_a1, j);
        for (int k = 0; k < EMB_DIM; ++k)
            c += g(emb, k) * g(W_a1, (2 + k) * ADJ_H + j);
        C[j]      = c;
        C[11 + j] = g(W_a1, 0 * ADJ_H + j);
        C[22 + j] = g(W_a1, 1 * ADJ_H + j);
        C[33 + j] = g(W_a2, j);
    }
    if (j == 0) C[44] = g(b_a2, 0);
}

// ---------------- MFMA GEMM: h = x @ W + b -> fp16, rows in PERM order ----------------
__global__ __launch_bounds__(256) void k_gemm_mfma(const void* __restrict__ xraw,
                                                   const int* __restrict__ flag,
                                                   const void* __restrict__ Wraw,
                                                   const void* __restrict__ braw,
                                                   const int* __restrict__ inv,
                                                   __half* __restrict__ out, int n) {
    __shared__ short Wt[64 * 520];
    int t = threadIdx.x;
    int isbf = *flag;
    if (isbf) {
        const unsigned short* wr = (const unsigned short*)Wraw;
        for (int e = t; e < FEATS * HIDDEN; e += 256)
            Wt[(e & 63) * 520 + (e >> 6)] = (short)wr[e];
    } else {
        const float* wr = (const float*)Wraw;
        for (int e = t; e < FEATS * HIDDEN; e += 256)
            Wt[(e & 63) * 520 + (e >> 6)] = (short)(__float_as_uint(wr[e]) >> 16);
    }
    __syncthreads();

    int wv = t >> 6;
    int lane = t & 63;
    int quad = lane >> 4, l16 = lane & 15;
    int rowbase = blockIdx.x * 256 + wv * 64;

    f32x4 acc[4][4];
    #pragma unroll
    for (int a = 0; a < 4; ++a)
        #pragma unroll
        for (int b = 0; b < 4; ++b)
            acc[a][b] = (f32x4){0.f, 0.f, 0.f, 0.f};

    if (isbf) {
        const short* x = (const short*)xraw;
        for (int ks = 0; ks < 16; ++ks) {
            short8 bfr[4];
            #pragma unroll
            for (int nt = 0; nt < 4; ++nt)
                bfr[nt] = *(const short8*)&Wt[(nt * 16 + l16) * 520 + ks * 32 + quad * 8];
            #pragma unroll
            for (int rt = 0; rt < 4; ++rt) {
                int arow = rowbase + rt * 16 + l16;
                if (arow >= n) arow = n - 1;
                short8 a = *(const short8*)(x + (size_t)arow * FEATS + ks * 32 + quad * 8);
                #pragma unroll
                for (int nt = 0; nt < 4; ++nt)
                    acc[rt][nt] = __builtin_amdgcn_mfma_f32_16x16x32_bf16(a, bfr[nt], acc[rt][nt], 0, 0, 0);
            }
        }
    } else {
        const float* x = (const float*)xraw;
        for (int ks = 0; ks < 16; ++ks) {
            short8 bfr[4];
            #pragma unroll
            for (int nt = 0; nt < 4; ++nt)
                bfr[nt] = *(const short8*)&Wt[(nt * 16 + l16) * 520 + ks * 32 + quad * 8];
            #pragma unroll
            for (int rt = 0; rt < 4; ++rt) {
                int arow = rowbase + rt * 16 + l16;
                if (arow >= n) arow = n - 1;
                const float* ap = x + (size_t)arow * FEATS + ks * 32 + quad * 8;
                short8 a;
                #pragma unroll
                for (int j = 0; j < 8; ++j)
                    a[j] = (short)(__float_as_uint(ap[j]) >> 16);
                #pragma unroll
                for (int nt = 0; nt < 4; ++nt)
                    acc[rt][nt] = __builtin_amdgcn_mfma_f32_16x16x32_bf16(a, bfr[nt], acc[rt][nt], 0, 0, 0);
            }
        }
    }

    float bias[4];
    #pragma unroll
    for (int nt = 0; nt < 4; ++nt)
        bias[nt] = isbf ? b2f(((const bf16*)braw)[nt * 16 + l16])
                        : ((const float*)braw)[nt * 16 + l16];

    #pragma unroll
    for (int rt = 0; rt < 4; ++rt)
        #pragma unroll
        for (int nt = 0; nt < 4; ++nt) {
            #pragma unroll
            for (int r = 0; r < 4; ++r) {
                int grow = rowbase + rt * 16 + quad * 4 + r;
                if (grow < n) {
                    int ir = inv[grow];
                    out[(size_t)ir * HIDDEN + nt * 16 + l16] =
                        __float2half(acc[rt][nt][r] + bias[nt]);
                }
            }
        }
}

// ---------------- conv sub-phase: gather only from one 3.2 MB src-row group ----------------
// 8 nodes/wave, 8 lanes/node (uint4 = 128-B fp16 row, 2 lines/edge — minimal line count).
// Partial sums carried across sub-dispatches as scaled fp16 in hio.
// Gather loads are PLAIN (need L2 residency); ew/h0 are NT loads (single-touch streams).
#define ACCROW(r, w)                                              \
    {                                                             \
        const unsigned* q_ = &(r).x;                              \
        _Pragma("unroll")                                         \
        for (int j_ = 0; j_ < 4; ++j_) {                          \
            float2 f_ = __half22float2(*(const __half2*)&q_[j_]); \
            acc[2 * j_]     += (w) * f_.x;                        \
            acc[2 * j_ + 1] += (w) * f_.y;                        \
        }                                                         \
    }

__global__ __launch_bounds__(256) void k_conv4(const int* __restrict__ starts,
                                               const unsigned short* __restrict__ lens,
                                               const unsigned* __restrict__ ew,
                                               const __half* __restrict__ hin,
                                               const __half* __restrict__ h0,
                                               __half* __restrict__ hio,
                                               int n, int doLoad, int doFinal) {
    int wv = (blockIdx.x * 256 + threadIdx.x) >> 6;
    int lane = threadIdx.x & 63;
    int sub = lane >> 3;          // 0..7 : node within wave
    int li  = lane & 7;           // 8 lanes x 8 fp16 = 128-B row
    int idx = wv * 8 + sub;
    bool valid = idx < n;
    int start = valid ? starts[idx] : 0;
    int end   = start + (valid ? (int)lens[idx] : 0);

    float acc[8];
    if (doLoad && valid) {
        uint4 pv = *(const uint4*)(hio + (size_t)idx * HIDDEN + li * 8);
        const unsigned* q = &pv.x;
        #pragma unroll
        for (int j = 0; j < 4; ++j) {
            float2 f = __half22float2(*(const __half2*)&q[j]);
            acc[2*j]   = 16384.0f * f.x;
            acc[2*j+1] = 16384.0f * f.y;
        }
    } else {
        #pragma unroll
        for (int j = 0; j < 8; ++j) acc[j] = 0.f;
    }

    int p = start;
    for (; p + 4 <= end; p += 4) {
        unsigned u0 = __builtin_nontemporal_load(&ew[p + 0]);
        unsigned u1 = __builtin_nontemporal_load(&ew[p + 1]);
        unsigned u2 = __builtin_nontemporal_load(&ew[p + 2]);
        unsigned u3 = __builtin_nontemporal_load(&ew[p + 3]);
        uint4 r0 = *(const uint4*)(hin + (size_t)(u0 >> 15) * HIDDEN + li * 8);
        uint4 r1 = *(const uint4*)(hin + (size_t)(u1 >> 15) * HIDDEN + li * 8);
        uint4 r2 = *(const uint4*)(hin + (size_t)(u2 >> 15) * HIDDEN + li * 8);
        uint4 r3 = *(const uint4*)(hin + (size_t)(u3 >> 15) * HIDDEN + li * 8);
        float w0 = (float)(u0 & 0x7FFFu);
        float w1 = (float)(u1 & 0x7FFFu);
        float w2 = (float)(u2 & 0x7FFFu);
        float w3 = (float)(u3 & 0x7FFFu);
        ACCROW(r0, w0); ACCROW(r1, w1); ACCROW(r2, w2); ACCROW(r3, w3);
    }
    for (; p < end; ++p) {
        unsigned u = __builtin_nontemporal_load(&ew[p]);
        uint4 r = *(const uint4*)(hin + (size_t)(u >> 15) * HIDDEN + li * 8);
        float w = (float)(u & 0x7FFFu);
        ACCROW(r, w);
    }

    if (valid) {
        size_t o = (size_t)idx * HIDDEN + li * 8;
        uint4 ov;
        unsigned* po = &ov.x;
        if (doFinal) {
            const unsigned long long* hp = (const unsigned long long*)(h0 + o);
            unsigned long long h01 = __builtin_nontemporal_load(hp + 0);
            unsigned long long h23 = __builtin_nontemporal_load(hp + 1);
            unsigned hq[4];
            hq[0] = (unsigned)h01; hq[1] = (unsigned)(h01 >> 32);
            hq[2] = (unsigned)h23; hq[3] = (unsigned)(h23 >> 32);
            #pragma unroll
            for (int j = 0; j < 4; ++j) {
                float2 g = __half22float2(*(const __half2*)&hq[j]);
                __half2 r = __floats2half2_rn(
                    0.9f * (1.0f / 16384.0f) * acc[2*j]   + 0.1f * g.x,
                    0.9f * (1.0f / 16384.0f) * acc[2*j+1] + 0.1f * g.y);
                po[j] = *(unsigned*)&r;
            }
        } else {
            #pragma unroll
            for (int j = 0; j < 4; ++j) {
                __half2 r = __floats2half2_rn((1.0f / 16384.0f) * acc[2*j],
                                              (1.0f / 16384.0f) * acc[2*j+1]);
                po[j] = *(unsigned*)&r;
            }
        }
        *(uint4*)(hio + o) = ov;   // plain store: next sub-dispatch / conv reads it
    }
}

// ---------------- elementwise edge-MLP (in-place on h0; order-agnostic) ----------------
__global__ __launch_bounds__(256) void k_mlp(__half* __restrict__ h0io,
                                             const __half* __restrict__ hc,
                                             const float* __restrict__ C, int total2) {
    int i = blockIdx.x * 256 + threadIdx.x;
    if (i >= total2) return;
    float2 hv  = __half22float2(((const __half2*)hc)[i]);
    float2 h0v = __half22float2(((const __half2*)h0io)[i]);
    float sx = C[44], sy = C[44];
    #pragma unroll
    for (int j = 0; j < ADJ_H; ++j) {
        float bj = C[j], wh = C[11 + j], w0 = C[22 + j], wo = C[33 + j];
        float zx = bj + hv.x * wh + h0v.x * w0;
        float zy = bj + hv.y * wh + h0v.y * w0;
        zx = (zx > 0.f) ? zx : 0.01f * zx;
        zy = (zy > 0.f) ? zy : 0.01f * zy;
        sx += zx * wo;
        sy += zy * wo;
    }
    ((__half2*)h0io)[i] = __floats2half2_rn(0.5f * sx, 0.5f * sy);
}

// ---------------- classifier: reads perm-ordered rows, writes natural order ----------------
__global__ __launch_bounds__(256) void k_cls(const __half* __restrict__ h,
                                             const int* __restrict__ perm,
                                             const void* __restrict__ Wcraw,
                                             const void* __restrict__ bcraw,
                                             void* __restrict__ outraw,
                                             const int* __restrict__ flag, int n) {
    __shared__ float hs[64][65];
    __shared__ float ws[64 * 16];
    __shared__ float bs[16];
    int t = threadIdx.x;
    int base = blockIdx.x * 64;
    int isbf = *flag;
    for (int it = 0; it < 16; ++it) {
        int e = it * 256 + t;
        int rr = e >> 6, cc = e & 63;
        int g = base + rr;
        hs[rr][cc] = (g < n) ? __half2float(h[(size_t)g * HIDDEN + cc]) : 0.f;
    }
    for (int it = 0; it < 4; ++it) {
        int e = it * 256 + t;
        ws[e] = isbf ? b2f(((const bf16*)Wcraw)[e]) : ((const float*)Wcraw)[e];
    }
    if (t < 16) bs[t] = isbf ? b2f(((const bf16*)bcraw)[t]) : ((const float*)bcraw)[t];
    __syncthreads();
    for (int q = 0; q < 4; ++q) {
        int e = q * 256 + t;
        int node = e >> 4, cls = e & 15;
        float acc = bs[cls];
        #pragma unroll 8
        for (int k = 0; k < HIDDEN; ++k)
            acc += hs[node][k] * ws[k * 16 + cls];
        int g = base + node;
        if (g < n) {
            int gn = perm[g];
            size_t oi = (size_t)gn * CLASSES + cls;
            if (isbf) ((bf16*)outraw)[oi] = __float2bfloat16(acc);
            else      ((float*)outraw)[oi] = acc;
        }
    }
}

extern "C" void kernel_launch(void* const* d_in, const int* in_sizes, int n_in,
                              void* d_out, int out_size, void* d_ws, size_t ws_size,
                              hipStream_t stream) {
    const void* x     = d_in[0];
    const int*  edges = (const int*)d_in[1];
    const void* W_dim = d_in[2];
    const void* b_dim = d_in[3];
    const void* emb   = d_in[4];
    const void* W_a1  = d_in[5];
    const void* b_a1  = d_in[6];
    const void* W_a2  = d_in[7];
    const void* b_a2  = d_in[8];
    const void* Wcls  = d_in[9];
    const void* bcls  = d_in[10];

    const int n = in_sizes[0] / FEATS;     // 100000
    const int E = in_sizes[1] / 2;         // 1600000
    const int m4 = NGRP * n;
    const int gsz = (n + NGRP - 1) / NGRP; // perm-rows per group

    char* w = (char*)d_ws;
    size_t off = 0;
    auto alloc = [&](size_t bytes) -> void* {
        void* p = w + off;
        off = (off + bytes + 255) & ~(size_t)255;
        return p;
    };
    // zero-initialized region first: deg, deg4, cursor4, hist
    int*      deg     = (int*)     alloc((size_t)n * 4);
    int*      deg4    = (int*)     alloc((size_t)m4 * 4);
    int*      cursor4 = (int*)     alloc((size_t)m4 * 4);
    int*      hist    = (int*)     alloc(256 * 4);
    size_t zero_bytes = off;
    int*      hcur    = (int*)     alloc(256 * 4);
    int*      perm    = (int*)     alloc((size_t)n * 4);
    int*      inv     = (int*)     alloc((size_t)n * 4);
    int*      offs4   = (int*)     alloc((size_t)(m4 + 1) * 4);
    int*      bsum    = (int*)     alloc(4096 * 4);
    int*      bpref   = (int*)     alloc(4096 * 4);
    unsigned* ew      = (unsigned*)alloc((size_t)E * 4);
    int*      startsS = (int*)     alloc((size_t)m4 * 4);
    unsigned short* lensS = (unsigned short*)alloc((size_t)m4 * 2);
    float*    consts  = (float*)   alloc(64 * 4);
    int*      flag    = (int*)     alloc(256);
    __half*   buf0    = (__half*)  alloc((size_t)n * HIDDEN * 2);
    __half*   bufA    = (__half*)  alloc((size_t)n * HIDDEN * 2);
    __half*   bufB    = (__half*)  alloc((size_t)n * HIDDEN * 2);

    int gE  = (E + 255) / 256;
    int gN  = (n + 255) / 256;
    int g4  = (m4 + 255) / 256;
    int nb4 = (m4 + 1023) / 1024;
    int gConv = (n + 31) / 32;   // 4 waves/block, 8 nodes/wave

    hipError_t _e = hipMemsetAsync(d_ws, 0, zero_bytes, stream);
    (void)_e;

    k_detect<<<1, 256, 0, stream>>>((const unsigned short*)x, flag);

    // degree + degree-sorted permutation
    k_deg    <<<gE, 256, 0, stream>>>(edges, deg, E);
    k_hist   <<<gN, 256, 0, stream>>>(deg, hist, n);
    k_hscan  <<<1, 256, 0, stream>>>(hist, hcur);
    k_scatter<<<gN, 256, 0, stream>>>(deg, hcur, perm, inv, n);

    // group-major CSR
    k_deg4 <<<gE, 256, 0, stream>>>(edges, inv, deg4, n, E, gsz);
    k_scan1<<<nb4, 256, 0, stream>>>(deg4, offs4, bsum, m4);
    k_scan2<<<1, 64, 0, stream>>>(bsum, bpref, offs4, nb4, m4);
    k_scan3<<<g4, 256, 0, stream>>>(offs4, bpref, m4);
    k_fill <<<gE, 256, 0, stream>>>(edges, inv, offs4, cursor4, deg, ew, n, E, gsz);
    k_meta <<<gN, 256, 0, stream>>>(perm, offs4, startsS, lensS, n);

    k_mlpconst<<<1, 64, 0, stream>>>(emb, W_a1, b_a1, W_a2, b_a2, flag, consts);

    k_gemm_mfma<<<(n + 255) / 256, 256, 0, stream>>>(x, flag, W_dim, b_dim, inv, buf0, n);

    // phase 1 diffusion: each conv = 4 sub-dispatches, one src-group each
    const __half* hin = buf0;
    for (int i = 0; i < DEPTH; ++i) {
        __half* ho = (i & 1) ? bufB : bufA;
        for (int s = 0; s < NGRP; ++s)
            k_conv4<<<gConv, 256, 0, stream>>>(startsS + (size_t)s * n,
                                               lensS + (size_t)s * n,
                                               ew, hin, buf0, ho, n,
                                               s > 0, s == NGRP - 1);
        hin = ho;
    }
    k_mlp<<<(n * (HIDDEN / 2) + 255) / 256, 256, 0, stream>>>(buf0, hin, consts, n * (HIDDEN / 2));

    // phase 2 diffusion
    hin = buf0;
    for (int i = 0; i < DEPTH; ++i) {
        __half* ho = (i & 1) ? bufB : bufA;
        for (int s = 0; s < NGRP; ++s)
            k_conv4<<<gConv, 256, 0, stream>>>(startsS + (size_t)s * n,
                                               lensS + (size_t)s * n,
                                               ew, hin, buf0, ho, n,
                                               s > 0, s == NGRP - 1);
        hin = ho;
    }
    k_cls<<<(n + 63) / 64, 256, 0, stream>>>(hin, perm, Wcls, bcls, d_out, flag, n);
}

// Round 6
// 1267.948 us; speedup vs baseline: 2.0275x; 1.5667x over previous
//
#include <hip/hip_runtime.h>
#include <hip/hip_bf16.h>
#include <hip/hip_fp16.h>
#include <stdint.h>

#define FEATS   512
#define HIDDEN  64
#define CLASSES 16
#define EMB_DIM 7
#define ADJ_H   11
#define DEPTH   10

typedef __hip_bfloat16 bf16;
typedef __attribute__((ext_vector_type(8))) short short8;
typedef __attribute__((ext_vector_type(4))) float f32x4;

__device__ __forceinline__ float b2f(bf16 v) { return __bfloat162float(v); }

// ---------------- dtype detect: 1 = bf16, 0 = f32 ----------------
__global__ void k_detect(const unsigned short* __restrict__ xs, int* __restrict__ flag) {
    __shared__ int cnt;
    if (threadIdx.x == 0) cnt = 0;
    __syncthreads();
    int c = 0;
    for (int i = threadIdx.x; i < 4096; i += 256) {
        unsigned e = (xs[i] >> 7) & 0xFFu;
        if (e >= 134u) c++;
    }
    atomicAdd(&cnt, c);
    __syncthreads();
    if (threadIdx.x == 0) *flag = (cnt < 64) ? 1 : 0;
}

// ---------------- degree ----------------
__global__ __launch_bounds__(256) void k_deg(const int* __restrict__ edges,
                                             int* __restrict__ deg, int E) {
    int e = blockIdx.x * 256 + threadIdx.x;
    if (e < E) atomicAdd(&deg[edges[E + e]], 1);
}

// ---------------- exclusive scan ----------------
__global__ __launch_bounds__(256) void k_scan1(const int* __restrict__ deg,
                                               int* __restrict__ offs,
                                               int* __restrict__ bsum, int n) {
    __shared__ int ts[256];
    int t = threadIdx.x;
    int base = blockIdx.x * 1024 + t * 4;
    int v0 = (base + 0 < n) ? deg[base + 0] : 0;
    int v1 = (base + 1 < n) ? deg[base + 1] : 0;
    int v2 = (base + 2 < n) ? deg[base + 2] : 0;
    int v3 = (base + 3 < n) ? deg[base + 3] : 0;
    int tsum = v0 + v1 + v2 + v3;
    ts[t] = tsum;
    __syncthreads();
    for (int d = 1; d < 256; d <<= 1) {
        int add = (t >= d) ? ts[t - d] : 0;
        __syncthreads();
        ts[t] += add;
        __syncthreads();
    }
    int excl = ts[t] - tsum;
    if (base + 0 < n) offs[base + 0] = excl;
    if (base + 1 < n) offs[base + 1] = excl + v0;
    if (base + 2 < n) offs[base + 2] = excl + v0 + v1;
    if (base + 3 < n) offs[base + 3] = excl + v0 + v1 + v2;
    if (t == 255) bsum[blockIdx.x] = ts[255];
}

__global__ void k_scan2(const int* __restrict__ bsum, int* __restrict__ bpref,
                        int* __restrict__ offs, int nb, int n) {
    if (threadIdx.x == 0 && blockIdx.x == 0) {
        int run = 0;
        int lim = (nb < 4096) ? nb : 4096;
        for (int i = 0; i < lim; ++i) { bpref[i] = run; run += bsum[i]; }
        offs[n] = run;
    }
}

__global__ __launch_bounds__(256) void k_scan3(int* __restrict__ offs,
                                               const int* __restrict__ bpref, int n) {
    int i = blockIdx.x * 256 + threadIdx.x;
    if (i < n) offs[i] += bpref[i >> 10];
}

// ---------------- CSR fill: pack (src:17b | w:15b fixed-point x16384) ----------------
__global__ __launch_bounds__(256) void k_fill(const int* __restrict__ edges,
                                              const int* __restrict__ offs,
                                              int* __restrict__ cursor,
                                              const int* __restrict__ deg,
                                              unsigned* __restrict__ ew, int E) {
    int e = blockIdx.x * 256 + threadIdx.x;
    if (e < E) {
        int src = edges[e];
        int dst = edges[E + e];
        int pos = offs[dst] + atomicAdd(&cursor[dst], 1);
        int ds = deg[src], dd = deg[dst];
        float w = (ds > 0 ? rsqrtf((float)ds) : 0.f) * (dd > 0 ? rsqrtf((float)dd) : 0.f);
        int w15 = (int)(w * 16384.0f + 0.5f);
        if (w15 > 32767) w15 = 32767;
        ew[pos] = ((unsigned)src << 15) | (unsigned)w15;
    }
}

// ---------------- MLP constants (reads raw dtype via flag) ----------------
__global__ void k_mlpconst(const void* __restrict__ emb, const void* __restrict__ W_a1,
                           const void* __restrict__ b_a1, const void* __restrict__ W_a2,
                           const void* __restrict__ b_a2, const int* __restrict__ flag,
                           float* __restrict__ C) {
    int isbf = *flag;
    auto g = [&](const void* p, int i) -> float {
        return isbf ? b2f(((const bf16*)p)[i]) : ((const float*)p)[i];
    };
    int j = threadIdx.x;
    if (j < ADJ_H) {
        float c = g(b_a1, j);
        for (int k = 0; k < EMB_DIM; ++k)
            c += g(emb, k) * g(W_a1, (2 + k) * ADJ_H + j);
        C[j]      = c;
        C[11 + j] = g(W_a1, 0 * ADJ_H + j);
        C[22 + j] = g(W_a1, 1 * ADJ_H + j);
        C[33 + j] = g(W_a2, j);
    }
    if (j == 0) C[44] = g(b_a2, 0);
}

// ---------------- MFMA GEMM: h = x @ W + b -> fp16 [node][64] ----------------
__global__ __launch_bounds__(256) void k_gemm_mfma(const void* __restrict__ xraw,
                                                   const int* __restrict__ flag,
                                                   const void* __restrict__ Wraw,
                                                   const void* __restrict__ braw,
                                                   __half* __restrict__ out, int n) {
    __shared__ short Wt[64 * 520];
    int t = threadIdx.x;
    int isbf = *flag;
    if (isbf) {
        const unsigned short* wr = (const unsigned short*)Wraw;
        for (int e = t; e < FEATS * HIDDEN; e += 256)
            Wt[(e & 63) * 520 + (e >> 6)] = (short)wr[e];
    } else {
        const float* wr = (const float*)Wraw;
        for (int e = t; e < FEATS * HIDDEN; e += 256)
            Wt[(e & 63) * 520 + (e >> 6)] = (short)(__float_as_uint(wr[e]) >> 16);
    }
    __syncthreads();

    int wv = t >> 6;
    int lane = t & 63;
    int quad = lane >> 4, l16 = lane & 15;
    int rowbase = blockIdx.x * 256 + wv * 64;

    f32x4 acc[4][4];
    #pragma unroll
    for (int a = 0; a < 4; ++a)
        #pragma unroll
        for (int b = 0; b < 4; ++b)
            acc[a][b] = (f32x4){0.f, 0.f, 0.f, 0.f};

    if (isbf) {
        const short* x = (const short*)xraw;
        for (int ks = 0; ks < 16; ++ks) {
            short8 bfr[4];
            #pragma unroll
            for (int nt = 0; nt < 4; ++nt)
                bfr[nt] = *(const short8*)&Wt[(nt * 16 + l16) * 520 + ks * 32 + quad * 8];
            #pragma unroll
            for (int rt = 0; rt < 4; ++rt) {
                int arow = rowbase + rt * 16 + l16;
                if (arow >= n) arow = n - 1;
                short8 a = *(const short8*)(x + (size_t)arow * FEATS + ks * 32 + quad * 8);
                #pragma unroll
                for (int nt = 0; nt < 4; ++nt)
                    acc[rt][nt] = __builtin_amdgcn_mfma_f32_16x16x32_bf16(a, bfr[nt], acc[rt][nt], 0, 0, 0);
            }
        }
    } else {
        const float* x = (const float*)xraw;
        for (int ks = 0; ks < 16; ++ks) {
            short8 bfr[4];
            #pragma unroll
            for (int nt = 0; nt < 4; ++nt)
                bfr[nt] = *(const short8*)&Wt[(nt * 16 + l16) * 520 + ks * 32 + quad * 8];
            #pragma unroll
            for (int rt = 0; rt < 4; ++rt) {
                int arow = rowbase + rt * 16 + l16;
                if (arow >= n) arow = n - 1;
                const float* ap = x + (size_t)arow * FEATS + ks * 32 + quad * 8;
                short8 a;
                #pragma unroll
                for (int j = 0; j < 8; ++j)
                    a[j] = (short)(__float_as_uint(ap[j]) >> 16);
                #pragma unroll
                for (int nt = 0; nt < 4; ++nt)
                    acc[rt][nt] = __builtin_amdgcn_mfma_f32_16x16x32_bf16(a, bfr[nt], acc[rt][nt], 0, 0, 0);
            }
        }
    }

    float bias[4];
    #pragma unroll
    for (int nt = 0; nt < 4; ++nt)
        bias[nt] = isbf ? b2f(((const bf16*)braw)[nt * 16 + l16])
                        : ((const float*)braw)[nt * 16 + l16];

    #pragma unroll
    for (int rt = 0; rt < 4; ++rt)
        #pragma unroll
        for (int nt = 0; nt < 4; ++nt) {
            #pragma unroll
            for (int r = 0; r < 4; ++r) {
                int grow = rowbase + rt * 16 + quad * 4 + r;
                if (grow < n)
                    out[(size_t)grow * HIDDEN + nt * 16 + l16] =
                        __float2half(acc[rt][nt][r] + bias[nt]);
            }
        }
}

// ---------------- conv: 8 nodes/wave, 8 lanes/node, 4-deep gather pipeline ----------------
// Line-traffic-bound at ~4 TB/s of 64B-line transactions (measured across 3 structural
// variants). 2 lines/edge is minimal for fp16x64 rows. ew/h0 single-touch streams are NT
// so they don't evict gather rows from L2.
__global__ __launch_bounds__(256) void k_conv(const int* __restrict__ offs,
                                              const unsigned* __restrict__ ew,
                                              const __half* __restrict__ hin,
                                              const __half* __restrict__ h0,
                                              __half* __restrict__ hout, int n) {
    int wv = (blockIdx.x * 256 + threadIdx.x) >> 6;
    int lane = threadIdx.x & 63;
    int sub = lane >> 3;          // 0..7 : node within wave
    int li  = lane & 7;           // 8 lanes x 8 fp16 = 128-B row
    int node = wv * 8 + sub;
    bool valid = node < n;
    int start = valid ? offs[node] : 0;
    int end   = valid ? offs[node + 1] : 0;

    float acc[8];
    #pragma unroll
    for (int j = 0; j < 8; ++j) acc[j] = 0.f;

    int p = start;
    for (; p + 4 <= end; p += 4) {
        unsigned u0 = __builtin_nontemporal_load(&ew[p + 0]);
        unsigned u1 = __builtin_nontemporal_load(&ew[p + 1]);
        unsigned u2 = __builtin_nontemporal_load(&ew[p + 2]);
        unsigned u3 = __builtin_nontemporal_load(&ew[p + 3]);
        uint4 r0 = *(const uint4*)(hin + (size_t)(u0 >> 15) * HIDDEN + li * 8);
        uint4 r1 = *(const uint4*)(hin + (size_t)(u1 >> 15) * HIDDEN + li * 8);
        uint4 r2 = *(const uint4*)(hin + (size_t)(u2 >> 15) * HIDDEN + li * 8);
        uint4 r3 = *(const uint4*)(hin + (size_t)(u3 >> 15) * HIDDEN + li * 8);
        float w0 = (float)(u0 & 0x7FFFu);
        float w1 = (float)(u1 & 0x7FFFu);
        float w2 = (float)(u2 & 0x7FFFu);
        float w3 = (float)(u3 & 0x7FFFu);
        const unsigned* q;
        q = &r0.x;
        #pragma unroll
        for (int j = 0; j < 4; ++j) {
            float2 f = __half22float2(*(const __half2*)&q[j]);
            acc[2*j]   += w0 * f.x;
            acc[2*j+1] += w0 * f.y;
        }
        q = &r1.x;
        #pragma unroll
        for (int j = 0; j < 4; ++j) {
            float2 f = __half22float2(*(const __half2*)&q[j]);
            acc[2*j]   += w1 * f.x;
            acc[2*j+1] += w1 * f.y;
        }
        q = &r2.x;
        #pragma unroll
        for (int j = 0; j < 4; ++j) {
            float2 f = __half22float2(*(const __half2*)&q[j]);
            acc[2*j]   += w2 * f.x;
            acc[2*j+1] += w2 * f.y;
        }
        q = &r3.x;
        #pragma unroll
        for (int j = 0; j < 4; ++j) {
            float2 f = __half22float2(*(const __half2*)&q[j]);
            acc[2*j]   += w3 * f.x;
            acc[2*j+1] += w3 * f.y;
        }
    }
    for (; p < end; ++p) {
        unsigned u = __builtin_nontemporal_load(&ew[p]);
        uint4 r = *(const uint4*)(hin + (size_t)(u >> 15) * HIDDEN + li * 8);
        float w = (float)(u & 0x7FFFu);
        const unsigned* q = &r.x;
        #pragma unroll
        for (int j = 0; j < 4; ++j) {
            float2 f = __half22float2(*(const __half2*)&q[j]);
            acc[2*j]   += w * f.x;
            acc[2*j+1] += w * f.y;
        }
    }

    if (valid) {
        size_t o = (size_t)node * HIDDEN + li * 8;
        const unsigned long long* hp = (const unsigned long long*)(h0 + o);
        unsigned long long h01 = __builtin_nontemporal_load(hp + 0);
        unsigned long long h23 = __builtin_nontemporal_load(hp + 1);
        unsigned hq[4];
        hq[0] = (unsigned)h01; hq[1] = (unsigned)(h01 >> 32);
        hq[2] = (unsigned)h23; hq[3] = (unsigned)(h23 >> 32);
        uint4 ov;
        unsigned* po = &ov.x;
        #pragma unroll
        for (int j = 0; j < 4; ++j) {
            float2 g = __half22float2(*(const __half2*)&hq[j]);
            __half2 r = __floats2half2_rn(
                0.9f * (1.0f / 16384.0f) * acc[2*j]   + 0.1f * g.x,
                0.9f * (1.0f / 16384.0f) * acc[2*j+1] + 0.1f * g.y);
            po[j] = *(unsigned*)&r;
        }
        *(uint4*)(hout + o) = ov;   // plain store: next conv gathers from it
    }
}

// ---------------- elementwise edge-MLP (in-place on h0) ----------------
__global__ __launch_bounds__(256) void k_mlp(__half* __restrict__ h0io,
                                             const __half* __restrict__ hc,
                                             const float* __restrict__ C, int total2) {
    int i = blockIdx.x * 256 + threadIdx.x;
    if (i >= total2) return;
    float2 hv  = __half22float2(((const __half2*)hc)[i]);
    float2 h0v = __half22float2(((const __half2*)h0io)[i]);
    float sx = C[44], sy = C[44];
    #pragma unroll
    for (int j = 0; j < ADJ_H; ++j) {
        float bj = C[j], wh = C[11 + j], w0 = C[22 + j], wo = C[33 + j];
        float zx = bj + hv.x * wh + h0v.x * w0;
        float zy = bj + hv.y * wh + h0v.y * w0;
        zx = (zx > 0.f) ? zx : 0.01f * zx;
        zy = (zy > 0.f) ? zy : 0.01f * zy;
        sx += zx * wo;
        sy += zy * wo;
    }
    ((__half2*)h0io)[i] = __floats2half2_rn(0.5f * sx, 0.5f * sy);
}

// ---------------- classifier ----------------
__global__ __launch_bounds__(256) void k_cls(const __half* __restrict__ h,
                                             const void* __restrict__ Wcraw,
                                             const void* __restrict__ bcraw,
                                             void* __restrict__ outraw,
                                             const int* __restrict__ flag, int n) {
    __shared__ float hs[64][65];
    __shared__ float ws[64 * 16];
    __shared__ float bs[16];
    int t = threadIdx.x;
    int base = blockIdx.x * 64;
    int isbf = *flag;
    for (int it = 0; it < 16; ++it) {
        int e = it * 256 + t;
        int rr = e >> 6, cc = e & 63;
        int g = base + rr;
        hs[rr][cc] = (g < n) ? __half2float(h[(size_t)g * HIDDEN + cc]) : 0.f;
    }
    for (int it = 0; it < 4; ++it) {
        int e = it * 256 + t;
        ws[e] = isbf ? b2f(((const bf16*)Wcraw)[e]) : ((const float*)Wcraw)[e];
    }
    if (t < 16) bs[t] = isbf ? b2f(((const bf16*)bcraw)[t]) : ((const float*)bcraw)[t];
    __syncthreads();
    for (int q = 0; q < 4; ++q) {
        int e = q * 256 + t;
        int node = e >> 4, cls = e & 15;
        float acc = bs[cls];
        #pragma unroll 8
        for (int k = 0; k < HIDDEN; ++k)
            acc += hs[node][k] * ws[k * 16 + cls];
        int g = base + node;
        if (g < n) {
            size_t oi = (size_t)g * CLASSES + cls;
            if (isbf) ((bf16*)outraw)[oi] = __float2bfloat16(acc);
            else      ((float*)outraw)[oi] = acc;
        }
    }
}

extern "C" void kernel_launch(void* const* d_in, const int* in_sizes, int n_in,
                              void* d_out, int out_size, void* d_ws, size_t ws_size,
                              hipStream_t stream) {
    const void* x     = d_in[0];
    const int*  edges = (const int*)d_in[1];
    const void* W_dim = d_in[2];
    const void* b_dim = d_in[3];
    const void* emb   = d_in[4];
    const void* W_a1  = d_in[5];
    const void* b_a1  = d_in[6];
    const void* W_a2  = d_in[7];
    const void* b_a2  = d_in[8];
    const void* Wcls  = d_in[9];
    const void* bcls  = d_in[10];

    const int n = in_sizes[0] / FEATS;     // 100000
    const int E = in_sizes[1] / 2;         // 1600000

    char* w = (char*)d_ws;
    size_t off = 0;
    auto alloc = [&](size_t bytes) -> void* {
        void* p = w + off;
        off = (off + bytes + 255) & ~(size_t)255;
        return p;
    };
    int*      deg    = (int*)     alloc((size_t)n * 4);
    int*      cursor = (int*)     alloc((size_t)n * 4);
    size_t zero_bytes = off;
    int*      offs   = (int*)     alloc((size_t)(n + 1) * 4);
    int*      bsum   = (int*)     alloc(4096 * 4);
    int*      bpref  = (int*)     alloc(4096 * 4);
    unsigned* ew     = (unsigned*)alloc((size_t)E * 4);
    float*    consts = (float*)   alloc(64 * 4);
    int*      flag   = (int*)     alloc(256);
    __half*   buf0   = (__half*)  alloc((size_t)n * HIDDEN * 2);
    __half*   bufA   = (__half*)  alloc((size_t)n * HIDDEN * 2);
    __half*   bufB   = (__half*)  alloc((size_t)n * HIDDEN * 2);

    int gE = (E + 255) / 256;
    int gN = (n + 255) / 256;
    int nb = (n + 1023) / 1024;
    int gConv = (n + 31) / 32;   // 4 waves/block, 8 nodes/wave

    hipError_t _e = hipMemsetAsync(d_ws, 0, zero_bytes, stream);
    (void)_e;

    k_detect<<<1, 256, 0, stream>>>((const unsigned short*)x, flag);

    k_deg  <<<gE, 256, 0, stream>>>(edges, deg, E);
    k_scan1<<<nb, 256, 0, stream>>>(deg, offs, bsum, n);
    k_scan2<<<1, 64, 0, stream>>>(bsum, bpref, offs, nb, n);
    k_scan3<<<gN, 256, 0, stream>>>(offs, bpref, n);
    k_fill <<<gE, 256, 0, stream>>>(edges, offs, cursor, deg, ew, E);

    k_mlpconst<<<1, 64, 0, stream>>>(emb, W_a1, b_a1, W_a2, b_a2, flag, consts);

    k_gemm_mfma<<<(n + 255) / 256, 256, 0, stream>>>(x, flag, W_dim, b_dim, buf0, n);

    const __half* hin = buf0;
    for (int i = 0; i < DEPTH; ++i) {
        __half* ho = (i & 1) ? bufB : bufA;
        k_conv<<<gConv, 256, 0, stream>>>(offs, ew, hin, buf0, ho, n);
        hin = ho;
    }
    k_mlp<<<(n * (HIDDEN / 2) + 255) / 256, 256, 0, stream>>>(buf0, hin, consts, n * (HIDDEN / 2));

    hin = buf0;
    for (int i = 0; i < DEPTH; ++i) {
        __half* ho = (i & 1) ? bufB : bufA;
        k_conv<<<gConv, 256, 0, stream>>>(offs, ew, hin, buf0, ho, n);
        hin = ho;
    }
    k_cls<<<(n + 63) / 64, 256, 0, stream>>>(hin, Wcls, bcls, d_out, flag, n);
}

// Round 7
// 1154.227 us; speedup vs baseline: 2.2273x; 1.0985x over previous
//
#include <hip/hip_runtime.h>
#include <hip/hip_bf16.h>
#include <hip/hip_fp16.h>
#include <stdint.h>

#define FEATS   512
#define HIDDEN  64
#define CLASSES 16
#define EMB_DIM 7
#define ADJ_H   11
#define DEPTH   10

typedef __hip_bfloat16 bf16;
typedef __attribute__((ext_vector_type(8))) short short8;
typedef __attribute__((ext_vector_type(4))) float f32x4;

__device__ __forceinline__ float b2f(bf16 v) { return __bfloat162float(v); }

// ---------------- dtype detect: 1 = bf16, 0 = f32 ----------------
__global__ void k_detect(const unsigned short* __restrict__ xs, int* __restrict__ flag) {
    __shared__ int cnt;
    if (threadIdx.x == 0) cnt = 0;
    __syncthreads();
    int c = 0;
    for (int i = threadIdx.x; i < 4096; i += 256) {
        unsigned e = (xs[i] >> 7) & 0xFFu;
        if (e >= 134u) c++;
    }
    atomicAdd(&cnt, c);
    __syncthreads();
    if (threadIdx.x == 0) *flag = (cnt < 64) ? 1 : 0;
}

// ---------------- degree ----------------
__global__ __launch_bounds__(256) void k_deg(const int* __restrict__ edges,
                                             int* __restrict__ deg, int E) {
    int e = blockIdx.x * 256 + threadIdx.x;
    if (e < E) atomicAdd(&deg[edges[E + e]], 1);
}

// ---------------- exclusive scan ----------------
__global__ __launch_bounds__(256) void k_scan1(const int* __restrict__ deg,
                                               int* __restrict__ offs,
                                               int* __restrict__ bsum, int n) {
    __shared__ int ts[256];
    int t = threadIdx.x;
    int base = blockIdx.x * 1024 + t * 4;
    int v0 = (base + 0 < n) ? deg[base + 0] : 0;
    int v1 = (base + 1 < n) ? deg[base + 1] : 0;
    int v2 = (base + 2 < n) ? deg[base + 2] : 0;
    int v3 = (base + 3 < n) ? deg[base + 3] : 0;
    int tsum = v0 + v1 + v2 + v3;
    ts[t] = tsum;
    __syncthreads();
    for (int d = 1; d < 256; d <<= 1) {
        int add = (t >= d) ? ts[t - d] : 0;
        __syncthreads();
        ts[t] += add;
        __syncthreads();
    }
    int excl = ts[t] - tsum;
    if (base + 0 < n) offs[base + 0] = excl;
    if (base + 1 < n) offs[base + 1] = excl + v0;
    if (base + 2 < n) offs[base + 2] = excl + v0 + v1;
    if (base + 3 < n) offs[base + 3] = excl + v0 + v1 + v2;
    if (t == 255) bsum[blockIdx.x] = ts[255];
}

__global__ void k_scan2(const int* __restrict__ bsum, int* __restrict__ bpref,
                        int* __restrict__ offs, int nb, int n) {
    if (threadIdx.x == 0 && blockIdx.x == 0) {
        int run = 0;
        int lim = (nb < 4096) ? nb : 4096;
        for (int i = 0; i < lim; ++i) { bpref[i] = run; run += bsum[i]; }
        offs[n] = run;
    }
}

__global__ __launch_bounds__(256) void k_scan3(int* __restrict__ offs,
                                               const int* __restrict__ bpref, int n) {
    int i = blockIdx.x * 256 + threadIdx.x;
    if (i < n) offs[i] += bpref[i >> 10];
}

// ---------------- CSR fill: pack (src:17b | w:15b fixed-point x16384) ----------------
__global__ __launch_bounds__(256) void k_fill(const int* __restrict__ edges,
                                              const int* __restrict__ offs,
                                              int* __restrict__ cursor,
                                              const int* __restrict__ deg,
                                              unsigned* __restrict__ ew, int E) {
    int e = blockIdx.x * 256 + threadIdx.x;
    if (e < E) {
        int src = edges[e];
        int dst = edges[E + e];
        int pos = offs[dst] + atomicAdd(&cursor[dst], 1);
        int ds = deg[src], dd = deg[dst];
        float w = (ds > 0 ? rsqrtf((float)ds) : 0.f) * (dd > 0 ? rsqrtf((float)dd) : 0.f);
        int w15 = (int)(w * 16384.0f + 0.5f);
        if (w15 > 32767) w15 = 32767;
        ew[pos] = ((unsigned)src << 15) | (unsigned)w15;
    }
}

// ---------------- MLP constants (reads raw dtype via flag) ----------------
__global__ void k_mlpconst(const void* __restrict__ emb, const void* __restrict__ W_a1,
                           const void* __restrict__ b_a1, const void* __restrict__ W_a2,
                           const void* __restrict__ b_a2, const int* __restrict__ flag,
                           float* __restrict__ C) {
    int isbf = *flag;
    auto g = [&](const void* p, int i) -> float {
        return isbf ? b2f(((const bf16*)p)[i]) : ((const float*)p)[i];
    };
    int j = threadIdx.x;
    if (j < ADJ_H) {
        float c = g(b_a1, j);
        for (int k = 0; k < EMB_DIM; ++k)
            c += g(emb, k) * g(W_a1, (2 + k) * ADJ_H + j);
        C[j]      = c;
        C[11 + j] = g(W_a1, 0 * ADJ_H + j);
        C[22 + j] = g(W_a1, 1 * ADJ_H + j);
        C[33 + j] = g(W_a2, j);
    }
    if (j == 0) C[44] = g(b_a2, 0);
}

// ---------------- MFMA GEMM: h = x @ W + b -> fp16 [node][64] ----------------
__global__ __launch_bounds__(256) void k_gemm_mfma(const void* __restrict__ xraw,
                                                   const int* __restrict__ flag,
                                                   const void* __restrict__ Wraw,
                                                   const void* __restrict__ braw,
                                                   __half* __restrict__ out, int n) {
    __shared__ short Wt[64 * 520];
    int t = threadIdx.x;
    int isbf = *flag;
    if (isbf) {
        const unsigned short* wr = (const unsigned short*)Wraw;
        for (int e = t; e < FEATS * HIDDEN; e += 256)
            Wt[(e & 63) * 520 + (e >> 6)] = (short)wr[e];
    } else {
        const float* wr = (const float*)Wraw;
        for (int e = t; e < FEATS * HIDDEN; e += 256)
            Wt[(e & 63) * 520 + (e >> 6)] = (short)(__float_as_uint(wr[e]) >> 16);
    }
    __syncthreads();

    int wv = t >> 6;
    int lane = t & 63;
    int quad = lane >> 4, l16 = lane & 15;
    int rowbase = blockIdx.x * 256 + wv * 64;

    f32x4 acc[4][4];
    #pragma unroll
    for (int a = 0; a < 4; ++a)
        #pragma unroll
        for (int b = 0; b < 4; ++b)
            acc[a][b] = (f32x4){0.f, 0.f, 0.f, 0.f};

    if (isbf) {
        const short* x = (const short*)xraw;
        for (int ks = 0; ks < 16; ++ks) {
            short8 bfr[4];
            #pragma unroll
            for (int nt = 0; nt < 4; ++nt)
                bfr[nt] = *(const short8*)&Wt[(nt * 16 + l16) * 520 + ks * 32 + quad * 8];
            #pragma unroll
            for (int rt = 0; rt < 4; ++rt) {
                int arow = rowbase + rt * 16 + l16;
                if (arow >= n) arow = n - 1;
                short8 a = *(const short8*)(x + (size_t)arow * FEATS + ks * 32 + quad * 8);
                #pragma unroll
                for (int nt = 0; nt < 4; ++nt)
                    acc[rt][nt] = __builtin_amdgcn_mfma_f32_16x16x32_bf16(a, bfr[nt], acc[rt][nt], 0, 0, 0);
            }
        }
    } else {
        const float* x = (const float*)xraw;
        for (int ks = 0; ks < 16; ++ks) {
            short8 bfr[4];
            #pragma unroll
            for (int nt = 0; nt < 4; ++nt)
                bfr[nt] = *(const short8*)&Wt[(nt * 16 + l16) * 520 + ks * 32 + quad * 8];
            #pragma unroll
            for (int rt = 0; rt < 4; ++rt) {
                int arow = rowbase + rt * 16 + l16;
                if (arow >= n) arow = n - 1;
                const float* ap = x + (size_t)arow * FEATS + ks * 32 + quad * 8;
                short8 a;
                #pragma unroll
                for (int j = 0; j < 8; ++j)
                    a[j] = (short)(__float_as_uint(ap[j]) >> 16);
                #pragma unroll
                for (int nt = 0; nt < 4; ++nt)
                    acc[rt][nt] = __builtin_amdgcn_mfma_f32_16x16x32_bf16(a, bfr[nt], acc[rt][nt], 0, 0, 0);
            }
        }
    }

    float bias[4];
    #pragma unroll
    for (int nt = 0; nt < 4; ++nt)
        bias[nt] = isbf ? b2f(((const bf16*)braw)[nt * 16 + l16])
                        : ((const float*)braw)[nt * 16 + l16];

    #pragma unroll
    for (int rt = 0; rt < 4; ++rt)
        #pragma unroll
        for (int nt = 0; nt < 4; ++nt) {
            #pragma unroll
            for (int r = 0; r < 4; ++r) {
                int grow = rowbase + rt * 16 + quad * 4 + r;
                if (grow < n)
                    out[(size_t)grow * HIDDEN + nt * 16 + l16] =
                        __float2half(acc[rt][nt][r] + bias[nt]);
            }
        }
}

// ---------------- conv: 8 nodes/wave, 8 lanes/node, 4-deep gather pipeline ----------------
// Verified at the random-line transaction ceiling (~4 TB/s of 64B-line traffic; invariant
// to cache residency per r3/r5 experiments). 2 lines/edge is minimal for fp16x64 rows.
// Plain loads everywhere: ew/h0 are re-read by all 20 convs and must stay LLC-resident
// (NT hints cost +117 us in r6).
__global__ __launch_bounds__(256) void k_conv(const int* __restrict__ offs,
                                              const unsigned* __restrict__ ew,
                                              const __half* __restrict__ hin,
                                              const __half* __restrict__ h0,
                                              __half* __restrict__ hout, int n) {
    int wv = (blockIdx.x * 256 + threadIdx.x) >> 6;
    int lane = threadIdx.x & 63;
    int sub = lane >> 3;          // 0..7 : node within wave
    int li  = lane & 7;           // 8 lanes x 8 fp16 = 128-B row
    int node = wv * 8 + sub;
    bool valid = node < n;
    int start = valid ? offs[node] : 0;
    int end   = valid ? offs[node + 1] : 0;

    float acc[8];
    #pragma unroll
    for (int j = 0; j < 8; ++j) acc[j] = 0.f;

    int p = start;
    for (; p + 4 <= end; p += 4) {
        unsigned u0 = ew[p + 0];
        unsigned u1 = ew[p + 1];
        unsigned u2 = ew[p + 2];
        unsigned u3 = ew[p + 3];
        uint4 r0 = *(const uint4*)(hin + (size_t)(u0 >> 15) * HIDDEN + li * 8);
        uint4 r1 = *(const uint4*)(hin + (size_t)(u1 >> 15) * HIDDEN + li * 8);
        uint4 r2 = *(const uint4*)(hin + (size_t)(u2 >> 15) * HIDDEN + li * 8);
        uint4 r3 = *(const uint4*)(hin + (size_t)(u3 >> 15) * HIDDEN + li * 8);
        float w0 = (float)(u0 & 0x7FFFu);
        float w1 = (float)(u1 & 0x7FFFu);
        float w2 = (float)(u2 & 0x7FFFu);
        float w3 = (float)(u3 & 0x7FFFu);
        const unsigned* q;
        q = &r0.x;
        #pragma unroll
        for (int j = 0; j < 4; ++j) {
            float2 f = __half22float2(*(const __half2*)&q[j]);
            acc[2*j]   += w0 * f.x;
            acc[2*j+1] += w0 * f.y;
        }
        q = &r1.x;
        #pragma unroll
        for (int j = 0; j < 4; ++j) {
            float2 f = __half22float2(*(const __half2*)&q[j]);
            acc[2*j]   += w1 * f.x;
            acc[2*j+1] += w1 * f.y;
        }
        q = &r2.x;
        #pragma unroll
        for (int j = 0; j < 4; ++j) {
            float2 f = __half22float2(*(const __half2*)&q[j]);
            acc[2*j]   += w2 * f.x;
            acc[2*j+1] += w2 * f.y;
        }
        q = &r3.x;
        #pragma unroll
        for (int j = 0; j < 4; ++j) {
            float2 f = __half22float2(*(const __half2*)&q[j]);
            acc[2*j]   += w3 * f.x;
            acc[2*j+1] += w3 * f.y;
        }
    }
    for (; p < end; ++p) {
        unsigned u = ew[p];
        uint4 r = *(const uint4*)(hin + (size_t)(u >> 15) * HIDDEN + li * 8);
        float w = (float)(u & 0x7FFFu);
        const unsigned* q = &r.x;
        #pragma unroll
        for (int j = 0; j < 4; ++j) {
            float2 f = __half22float2(*(const __half2*)&q[j]);
            acc[2*j]   += w * f.x;
            acc[2*j+1] += w * f.y;
        }
    }

    if (valid) {
        size_t o = (size_t)node * HIDDEN + li * 8;
        uint4 hv = *(const uint4*)(h0 + o);
        const unsigned* q = &hv.x;
        uint4 ov;
        unsigned* po = &ov.x;
        #pragma unroll
        for (int j = 0; j < 4; ++j) {
            float2 g = __half22float2(*(const __half2*)&q[j]);
            __half2 r = __floats2half2_rn(
                0.9f * (1.0f / 16384.0f) * acc[2*j]   + 0.1f * g.x,
                0.9f * (1.0f / 16384.0f) * acc[2*j+1] + 0.1f * g.y);
            po[j] = *(unsigned*)&r;
        }
        *(uint4*)(hout + o) = ov;
    }
}

// ---------------- elementwise edge-MLP (in-place on h0) ----------------
__global__ __launch_bounds__(256) void k_mlp(__half* __restrict__ h0io,
                                             const __half* __restrict__ hc,
                                             const float* __restrict__ C, int total2) {
    int i = blockIdx.x * 256 + threadIdx.x;
    if (i >= total2) return;
    float2 hv  = __half22float2(((const __half2*)hc)[i]);
    float2 h0v = __half22float2(((const __half2*)h0io)[i]);
    float sx = C[44], sy = C[44];
    #pragma unroll
    for (int j = 0; j < ADJ_H; ++j) {
        float bj = C[j], wh = C[11 + j], w0 = C[22 + j], wo = C[33 + j];
        float zx = bj + hv.x * wh + h0v.x * w0;
        float zy = bj + hv.y * wh + h0v.y * w0;
        zx = (zx > 0.f) ? zx : 0.01f * zx;
        zy = (zy > 0.f) ? zy : 0.01f * zy;
        sx += zx * wo;
        sy += zy * wo;
    }
    ((__half2*)h0io)[i] = __floats2half2_rn(0.5f * sx, 0.5f * sy);
}

// ---------------- classifier ----------------
__global__ __launch_bounds__(256) void k_cls(const __half* __restrict__ h,
                                             const void* __restrict__ Wcraw,
                                             const void* __restrict__ bcraw,
                                             void* __restrict__ outraw,
                                             const int* __restrict__ flag, int n) {
    __shared__ float hs[64][65];
    __shared__ float ws[64 * 16];
    __shared__ float bs[16];
    int t = threadIdx.x;
    int base = blockIdx.x * 64;
    int isbf = *flag;
    for (int it = 0; it < 16; ++it) {
        int e = it * 256 + t;
        int rr = e >> 6, cc = e & 63;
        int g = base + rr;
        hs[rr][cc] = (g < n) ? __half2float(h[(size_t)g * HIDDEN + cc]) : 0.f;
    }
    for (int it = 0; it < 4; ++it) {
        int e = it * 256 + t;
        ws[e] = isbf ? b2f(((const bf16*)Wcraw)[e]) : ((const float*)Wcraw)[e];
    }
    if (t < 16) bs[t] = isbf ? b2f(((const bf16*)bcraw)[t]) : ((const float*)bcraw)[t];
    __syncthreads();
    for (int q = 0; q < 4; ++q) {
        int e = q * 256 + t;
        int node = e >> 4, cls = e & 15;
        float acc = bs[cls];
        #pragma unroll 8
        for (int k = 0; k < HIDDEN; ++k)
            acc += hs[node][k] * ws[k * 16 + cls];
        int g = base + node;
        if (g < n) {
            size_t oi = (size_t)g * CLASSES + cls;
            if (isbf) ((bf16*)outraw)[oi] = __float2bfloat16(acc);
            else      ((float*)outraw)[oi] = acc;
        }
    }
}

extern "C" void kernel_launch(void* const* d_in, const int* in_sizes, int n_in,
                              void* d_out, int out_size, void* d_ws, size_t ws_size,
                              hipStream_t stream) {
    const void* x     = d_in[0];
    const int*  edges = (const int*)d_in[1];
    const void* W_dim = d_in[2];
    const void* b_dim = d_in[3];
    const void* emb   = d_in[4];
    const void* W_a1  = d_in[5];
    const void* b_a1  = d_in[6];
    const void* W_a2  = d_in[7];
    const void* b_a2  = d_in[8];
    const void* Wcls  = d_in[9];
    const void* bcls  = d_in[10];

    const int n = in_sizes[0] / FEATS;     // 100000
    const int E = in_sizes[1] / 2;         // 1600000

    char* w = (char*)d_ws;
    size_t off = 0;
    auto alloc = [&](size_t bytes) -> void* {
        void* p = w + off;
        off = (off + bytes + 255) & ~(size_t)255;
        return p;
    };
    int*      deg    = (int*)     alloc((size_t)n * 4);
    int*      cursor = (int*)     alloc((size_t)n * 4);
    size_t zero_bytes = off;
    int*      offs   = (int*)     alloc((size_t)(n + 1) * 4);
    int*      bsum   = (int*)     alloc(4096 * 4);
    int*      bpref  = (int*)     alloc(4096 * 4);
    unsigned* ew     = (unsigned*)alloc((size_t)E * 4);
    float*    consts = (float*)   alloc(64 * 4);
    int*      flag   = (int*)     alloc(256);
    __half*   buf0   = (__half*)  alloc((size_t)n * HIDDEN * 2);
    __half*   bufA   = (__half*)  alloc((size_t)n * HIDDEN * 2);
    __half*   bufB   = (__half*)  alloc((size_t)n * HIDDEN * 2);

    int gE = (E + 255) / 256;
    int gN = (n + 255) / 256;
    int nb = (n + 1023) / 1024;
    int gConv = (n + 31) / 32;   // 4 waves/block, 8 nodes/wave

    hipError_t _e = hipMemsetAsync(d_ws, 0, zero_bytes, stream);
    (void)_e;

    k_detect<<<1, 256, 0, stream>>>((const unsigned short*)x, flag);

    k_deg  <<<gE, 256, 0, stream>>>(edges, deg, E);
    k_scan1<<<nb, 256, 0, stream>>>(deg, offs, bsum, n);
    k_scan2<<<1, 64, 0, stream>>>(bsum, bpref, offs, nb, n);
    k_scan3<<<gN, 256, 0, stream>>>(offs, bpref, n);
    k_fill <<<gE, 256, 0, stream>>>(edges, offs, cursor, deg, ew, E);

    k_mlpconst<<<1, 64, 0, stream>>>(emb, W_a1, b_a1, W_a2, b_a2, flag, consts);

    k_gemm_mfma<<<(n + 255) / 256, 256, 0, stream>>>(x, flag, W_dim, b_dim, buf0, n);

    const __half* hin = buf0;
    for (int i = 0; i < DEPTH; ++i) {
        __half* ho = (i & 1) ? bufB : bufA;
        k_conv<<<gConv, 256, 0, stream>>>(offs, ew, hin, buf0, ho, n);
        hin = ho;
    }
    k_mlp<<<(n * (HIDDEN / 2) + 255) / 256, 256, 0, stream>>>(buf0, hin, consts, n * (HIDDEN / 2));

    hin = buf0;
    for (int i = 0; i < DEPTH; ++i) {
        __half* ho = (i & 1) ? bufB : bufA;
        k_conv<<<gConv, 256, 0, stream>>>(offs, ew, hin, buf0, ho, n);
        hin = ho;
    }
    k_cls<<<(n + 63) / 64, 256, 0, stream>>>(hin, Wcls, bcls, d_out, flag, n);
}